// Round 1
// baseline (30698.956 us; speedup 1.0000x reference)
//
#include <hip/hip_runtime.h>
#include <math.h>

// Problem constants (fixed by setup_inputs)
#define B 2048
#define T 128
#define H 512
#define NC 3
#define NO 5
#define IN_DIM 8   // NO + NC

// GEMM tiling: 64x64 block tile, BK=32, 256 threads, 4x4 register tile x 3 gates
#define BM 64
#define BN 64
#define BK 32
#define PKA 36   // sA row pad (floats): stride 36 -> broadcast/2-way-free LDS reads
#define PNW 68   // sW n pad (floats): 16B-aligned float4 reads, benign write conflicts

__device__ __forceinline__ float sigmoidf_(float x) {
    return 1.0f / (1.0f + __expf(-x));
}

// Accumulate acc[g][mi][ni] += sum_k A[b0+ty*4+mi][k] * W[(g*H + n0+tx*4+ni)*H + k]
// A: B x H row-major. W: 3H x H row-major.
__device__ __forceinline__ void gemm3_acc(
    const float* __restrict__ A,
    const float* __restrict__ W,
    int b0, int n0, int tid, int tx, int ty,
    float (*sA)[PKA], float (*sW)[BK][PNW],
    float (&acc)[3][4][4])
{
    const int lm = tid >> 2;          // 0..63
    const int lk = (tid & 3) * 8;     // 0,8,16,24

    for (int kt = 0; kt < H / BK; ++kt) {
        const int k0 = kt * BK;
        __syncthreads();   // protect previous tile's reads before overwrite
        // ---- stage A tile: sA[m][k] ----
        {
            const float* src = A + (size_t)(b0 + lm) * H + k0 + lk;
            float4 v0 = *(const float4*)(src);
            float4 v1 = *(const float4*)(src + 4);
            *(float4*)&sA[lm][lk]     = v0;
            *(float4*)&sA[lm][lk + 4] = v1;
        }
        // ---- stage W tiles: sW[g][k][n] (transposed for float4 n-reads) ----
        #pragma unroll
        for (int g = 0; g < 3; ++g) {
            const float* src = W + (size_t)(g * H + n0 + lm) * H + k0 + lk;
            float4 v0 = *(const float4*)(src);
            float4 v1 = *(const float4*)(src + 4);
            sW[g][lk + 0][lm] = v0.x; sW[g][lk + 1][lm] = v0.y;
            sW[g][lk + 2][lm] = v0.z; sW[g][lk + 3][lm] = v0.w;
            sW[g][lk + 4][lm] = v1.x; sW[g][lk + 5][lm] = v1.y;
            sW[g][lk + 6][lm] = v1.z; sW[g][lk + 7][lm] = v1.w;
        }
        __syncthreads();
        // ---- compute ----
        #pragma unroll 4
        for (int k = 0; k < BK; ++k) {
            float av[4];
            #pragma unroll
            for (int mi = 0; mi < 4; ++mi) av[mi] = sA[ty * 4 + mi][k];
            #pragma unroll
            for (int g = 0; g < 3; ++g) {
                float4 w = *(const float4*)&sW[g][k][tx * 4];
                float wv[4] = {w.x, w.y, w.z, w.w};
                #pragma unroll
                for (int mi = 0; mi < 4; ++mi)
                    #pragma unroll
                    for (int ni = 0; ni < 4; ++ni)
                        acc[g][mi][ni] = fmaf(av[mi], wv[ni], acc[g][mi][ni]);
            }
        }
    }
}

// Layer-1 GRU step: h1_new = GRUCell(x=[y,cmd], h1_prev). grid (B/BM, H/BN), block 256.
__global__ __launch_bounds__(256) void gru1_kernel(
    const float* __restrict__ y_prev,   // B x NO
    const float* __restrict__ cmd_t,    // B x NC
    const float* __restrict__ h1_prev,  // B x H
    const float* __restrict__ W_ih1,    // 3H x IN_DIM
    const float* __restrict__ W_hh1,    // 3H x H
    const float* __restrict__ b_ih1,    // 3H
    const float* __restrict__ b_hh1,    // 3H
    float* __restrict__ h1_new)         // B x H
{
    __shared__ float sA[BM][PKA];
    __shared__ float sW[3][BK][PNW];
    __shared__ float sX[BM][IN_DIM];
    __shared__ float sWih[3][IN_DIM][PNW];
    __shared__ float sbi[3][BN], sbh[3][BN];

    const int tid = threadIdx.x;
    const int tx = tid & 15;
    const int ty = tid >> 4;
    const int b0 = blockIdx.x * BM;
    const int n0 = blockIdx.y * BN;

    // one-time staging (visibility covered by the syncs inside gemm3_acc)
    if (tid < BM) {
        const float* yr = y_prev + (size_t)(b0 + tid) * NO;
        const float* cr = cmd_t + (size_t)(b0 + tid) * NC;
        #pragma unroll
        for (int j = 0; j < NO; ++j) sX[tid][j] = yr[j];
        #pragma unroll
        for (int j = 0; j < NC; ++j) sX[tid][NO + j] = cr[j];
    }
    if (tid < 192) {
        const int g = tid / 64, nn = tid % 64;
        const float* wr = W_ih1 + (size_t)(g * H + n0 + nn) * IN_DIM;
        #pragma unroll
        for (int k = 0; k < IN_DIM; ++k) sWih[g][k][nn] = wr[k];
        sbi[g][nn] = b_ih1[g * H + n0 + nn];
        sbh[g][nn] = b_hh1[g * H + n0 + nn];
    }

    float acc[3][4][4];
    #pragma unroll
    for (int g = 0; g < 3; ++g)
        #pragma unroll
        for (int i = 0; i < 4; ++i)
            #pragma unroll
            for (int j = 0; j < 4; ++j) acc[g][i][j] = 0.f;

    gemm3_acc(h1_prev, W_hh1, b0, n0, tid, tx, ty, sA, sW, acc);

    // epilogue: gi (K=8) + gates + blend
    #pragma unroll
    for (int mi = 0; mi < 4; ++mi) {
        const int ml = ty * 4 + mi;
        const int m = b0 + ml;
        float xv[IN_DIM];
        #pragma unroll
        for (int k = 0; k < IN_DIM; ++k) xv[k] = sX[ml][k];
        float4 hp4 = *(const float4*)(h1_prev + (size_t)m * H + n0 + tx * 4);
        float hpv[4] = {hp4.x, hp4.y, hp4.z, hp4.w};
        float outv[4];
        #pragma unroll
        for (int ni = 0; ni < 4; ++ni) {
            const int nl = tx * 4 + ni;
            float gi0 = sbi[0][nl], gi1 = sbi[1][nl], gi2 = sbi[2][nl];
            #pragma unroll
            for (int k = 0; k < IN_DIM; ++k) {
                gi0 = fmaf(xv[k], sWih[0][k][nl], gi0);
                gi1 = fmaf(xv[k], sWih[1][k][nl], gi1);
                gi2 = fmaf(xv[k], sWih[2][k][nl], gi2);
            }
            const float ghr = acc[0][mi][ni] + sbh[0][nl];
            const float ghz = acc[1][mi][ni] + sbh[1][nl];
            const float ghn = acc[2][mi][ni] + sbh[2][nl];
            const float r = sigmoidf_(gi0 + ghr);
            const float z = sigmoidf_(gi1 + ghz);
            const float n = tanhf(fmaf(r, ghn, gi2));
            outv[ni] = (1.f - z) * n + z * hpv[ni];
        }
        *(float4*)(h1_new + (size_t)m * H + n0 + tx * 4) = *(float4*)outv;
    }
}

// Layer-2 GRU step: h2_new = GRUCell(h1_cur, h2_prev). grid (B/BM, H/BN), block 256.
__global__ __launch_bounds__(256) void gru2_kernel(
    const float* __restrict__ h1_cur,   // B x H
    const float* __restrict__ h2_prev,  // B x H
    const float* __restrict__ W_ih2,    // 3H x H
    const float* __restrict__ W_hh2,    // 3H x H
    const float* __restrict__ b_ih2,
    const float* __restrict__ b_hh2,
    float* __restrict__ h2_new)
{
    __shared__ float sA[BM][PKA];
    __shared__ float sW[3][BK][PNW];
    __shared__ float sbi[3][BN], sbh[3][BN];

    const int tid = threadIdx.x;
    const int tx = tid & 15;
    const int ty = tid >> 4;
    const int b0 = blockIdx.x * BM;
    const int n0 = blockIdx.y * BN;

    if (tid < 192) {
        const int g = tid / 64, nn = tid % 64;
        sbi[g][nn] = b_ih2[g * H + n0 + nn];
        sbh[g][nn] = b_hh2[g * H + n0 + nn];
    }

    float acci[3][4][4], acch[3][4][4];
    #pragma unroll
    for (int g = 0; g < 3; ++g)
        #pragma unroll
        for (int i = 0; i < 4; ++i)
            #pragma unroll
            for (int j = 0; j < 4; ++j) { acci[g][i][j] = 0.f; acch[g][i][j] = 0.f; }

    gemm3_acc(h1_cur,  W_ih2, b0, n0, tid, tx, ty, sA, sW, acci);
    gemm3_acc(h2_prev, W_hh2, b0, n0, tid, tx, ty, sA, sW, acch);

    #pragma unroll
    for (int mi = 0; mi < 4; ++mi) {
        const int m = b0 + ty * 4 + mi;
        float4 hp4 = *(const float4*)(h2_prev + (size_t)m * H + n0 + tx * 4);
        float hpv[4] = {hp4.x, hp4.y, hp4.z, hp4.w};
        float outv[4];
        #pragma unroll
        for (int ni = 0; ni < 4; ++ni) {
            const int nl = tx * 4 + ni;
            const float gir = acci[0][mi][ni] + sbi[0][nl];
            const float giz = acci[1][mi][ni] + sbi[1][nl];
            const float gin = acci[2][mi][ni] + sbi[2][nl];
            const float ghr = acch[0][mi][ni] + sbh[0][nl];
            const float ghz = acch[1][mi][ni] + sbh[1][nl];
            const float ghn = acch[2][mi][ni] + sbh[2][nl];
            const float r = sigmoidf_(gir + ghr);
            const float z = sigmoidf_(giz + ghz);
            const float n = tanhf(fmaf(r, ghn, gin));
            outv[ni] = (1.f - z) * n + z * hpv[ni];
        }
        *(float4*)(h2_new + (size_t)m * H + n0 + tx * 4) = *(float4*)outv;
    }
}

// y = h2 @ W_out.T + b_out; writes compact ybuf (for next step's x) and d_out[b][t][:].
__global__ void yout_kernel(const float* __restrict__ h2,
                            const float* __restrict__ W_out,  // NO x H
                            const float* __restrict__ b_out,  // NO
                            float* __restrict__ ybuf,         // B x NO
                            float* __restrict__ out,          // B x T x NO
                            int t)
{
    const int idx = blockIdx.x * blockDim.x + threadIdx.x;
    if (idx >= B * NO) return;
    const int b = idx / NO;
    const int o = idx - b * NO;
    const float* h = h2 + (size_t)b * H;
    const float* w = W_out + (size_t)o * H;
    float acc = b_out[o];
    #pragma unroll 4
    for (int k = 0; k < H; k += 4) {
        float4 hv = *(const float4*)(h + k);
        float4 wv = *(const float4*)(w + k);
        acc = fmaf(hv.x, wv.x, acc);
        acc = fmaf(hv.y, wv.y, acc);
        acc = fmaf(hv.z, wv.z, acc);
        acc = fmaf(hv.w, wv.w, acc);
    }
    ybuf[idx] = acc;
    out[(size_t)b * (T * NO) + (size_t)t * NO + o] = acc;
}

extern "C" void kernel_launch(void* const* d_in, const int* in_sizes, int n_in,
                              void* d_out, int out_size, void* d_ws, size_t ws_size,
                              hipStream_t stream) {
    // setup_inputs order:
    // 0 predict_len (int, always 128 — unused), 1 rnn_input_commands (T,B,NC),
    // 2 y0 (B,NO), 3 h0_1 (B,H), 4 h0_2 (B,H),
    // 5 W_ih1 (3H,IN_DIM), 6 W_hh1 (3H,H), 7 b_ih1, 8 b_hh1,
    // 9 W_ih2 (3H,H), 10 W_hh2 (3H,H), 11 b_ih2, 12 b_hh2,
    // 13 W_out (NO,H), 14 b_out (NO)
    const float* cmds  = (const float*)d_in[1];
    const float* y0    = (const float*)d_in[2];
    const float* h01   = (const float*)d_in[3];
    const float* h02   = (const float*)d_in[4];
    const float* W_ih1 = (const float*)d_in[5];
    const float* W_hh1 = (const float*)d_in[6];
    const float* b_ih1 = (const float*)d_in[7];
    const float* b_hh1 = (const float*)d_in[8];
    const float* W_ih2 = (const float*)d_in[9];
    const float* W_hh2 = (const float*)d_in[10];
    const float* b_ih2 = (const float*)d_in[11];
    const float* b_hh2 = (const float*)d_in[12];
    const float* W_out = (const float*)d_in[13];
    const float* b_out = (const float*)d_in[14];
    float* out = (float*)d_out;

    // workspace: 2x h1 (4MB each) + 2x h2 + ybuf = ~16.04 MB
    const size_t HBUF = (size_t)B * H;
    float* ws = (float*)d_ws;
    float* h1b[2] = {ws, ws + HBUF};
    float* h2b[2] = {ws + 2 * HBUF, ws + 3 * HBUF};
    float* ybuf = ws + 4 * HBUF;

    const float* y_prev  = y0;
    const float* h1_prev = h01;
    const float* h2_prev = h02;

    const dim3 gridG(B / BM, H / BN);   // (32, 8)
    for (int t = 0; t < T; ++t) {
        float* h1_cur = h1b[t & 1];
        float* h2_cur = h2b[t & 1];
        gru1_kernel<<<gridG, 256, 0, stream>>>(y_prev, cmds + (size_t)t * B * NC, h1_prev,
                                               W_ih1, W_hh1, b_ih1, b_hh1, h1_cur);
        gru2_kernel<<<gridG, 256, 0, stream>>>(h1_cur, h2_prev, W_ih2, W_hh2,
                                               b_ih2, b_hh2, h2_cur);
        yout_kernel<<<(B * NO + 255) / 256, 256, 0, stream>>>(h2_cur, W_out, b_out,
                                                              ybuf, out, t);
        y_prev  = ybuf;
        h1_prev = h1_cur;
        h2_prev = h2_cur;
    }
}

// Round 3
// 11095.734 us; speedup vs baseline: 2.7667x; 2.7667x over previous
//
#include <hip/hip_runtime.h>
#include <math.h>

// Problem constants
#define B 2048
#define T 128
#define H 512
#define NC 3
#define NO 5
#define G3H 1536   // 3*H

typedef _Float16 half8 __attribute__((ext_vector_type(8)));
typedef float float4v __attribute__((ext_vector_type(4)));

#define LO_SCALE 1024.0f
#define INV_LO (1.0f / 1024.0f)
#define F16_MIN_NORM 6.103515625e-05f

__device__ __forceinline__ float sigmoidf_(float x) {
    return 1.0f / (1.0f + __expf(-x));
}

// Split fp32 -> (hi, lo*1024) f16 pair. hi forced to 0 in subnormal range so the
// scaled lo lane carries the value (MFMA input-denorm-flush safety).
__device__ __forceinline__ void split_f16(float a, _Float16* hi, _Float16* lo) {
    _Float16 h = (_Float16)a;
    if (fabsf(a) < F16_MIN_NORM) h = (_Float16)0.0f;
    *hi = h;
    *lo = (_Float16)((a - (float)h) * LO_SCALE);
}

// async 16B global->LDS (wave-uniform LDS base; lane lands at base + lane*16B)
__device__ __forceinline__ void stage16(const _Float16* gp, _Float16* lp) {
    __builtin_amdgcn_global_load_lds(
        (const __attribute__((address_space(1))) unsigned int*)gp,
        (__attribute__((address_space(3))) unsigned int*)lp,
        16, 0, 0);
}

// ---------------- prep kernels ----------------

// split the three big weight matrices (1536x512) into f16 hi/lo pairs
__global__ void conv3_kernel(const float* __restrict__ w1, const float* __restrict__ w2,
                             const float* __restrict__ w3,
                             _Float16* o1h, _Float16* o1l, _Float16* o2h, _Float16* o2l,
                             _Float16* o3h, _Float16* o3l) {
    int i = blockIdx.x * 256 + threadIdx.x;
    if (i < G3H * H) {
        split_f16(w1[i], &o1h[i], &o1l[i]);
        split_f16(w2[i], &o2h[i], &o2l[i]);
        split_f16(w3[i], &o3h[i], &o3l[i]);
    }
}

// wi1p (1536x64 zero-padded W_ih1) hi/lo, h0 splits, initial xpad=[y0,cmd0,0...]
__global__ void prep_kernel(const float* __restrict__ Wih1,
                            const float* __restrict__ h01, const float* __restrict__ h02,
                            const float* __restrict__ y0, const float* __restrict__ cmd0,
                            _Float16* wi1ph, _Float16* wi1pl,
                            _Float16* h1h, _Float16* h1l, _Float16* h2h, _Float16* h2l,
                            _Float16* xph, _Float16* xpl) {
    int i = blockIdx.x * 256 + threadIdx.x;
    if (i < B * H) {
        split_f16(h01[i], &h1h[i], &h1l[i]);
        split_f16(h02[i], &h2h[i], &h2l[i]);
    }
    if (i < G3H * 64) {
        int r = i >> 6, c = i & 63;
        float v = (c < 8) ? Wih1[r * 8 + c] : 0.0f;
        split_f16(v, &wi1ph[i], &wi1pl[i]);
    }
    if (i < B * 64) {
        int r = i >> 6, c = i & 63;
        float v = (c < NO) ? y0[r * NO + c] : ((c < 8) ? cmd0[r * NC + (c - NO)] : 0.0f);
        split_f16(v, &xph[i], &xpl[i]);
    }
}

// ---------------- fused split-f16 GRU cell ----------------
// phase 0: gi = Ai @ Wi^T (itersI * K64), phase 1: gh = Ah @ Wh^T (itersH * K64)
// acc sets: 0=r (both phases), 1=z (both), 2=i_n, 3=h_n. Each has hi + lo accum.
// grid: 256 blocks (bid&7 -> n-tile => XCD-local W slice; bid>>3 -> m-tile).
__global__ __launch_bounds__(256, 1) void gru_cell_kernel(
    const _Float16* __restrict__ Aih, const _Float16* __restrict__ Ail, int ldAi,
    const _Float16* __restrict__ Wih_, const _Float16* __restrict__ Wil_, int ldWi, int itersI,
    const _Float16* __restrict__ Ahh_, const _Float16* __restrict__ Ahl_,
    const _Float16* __restrict__ Whh_, const _Float16* __restrict__ Whl_, int itersH,
    const float* __restrict__ b_i, const float* __restrict__ b_h,
    const _Float16* __restrict__ hph, const _Float16* __restrict__ hpl,
    _Float16* __restrict__ hnh, _Float16* __restrict__ hnl)
{
    __shared__ _Float16 sAh[2][4096];    // [buf][m(64)][k(64)]
    __shared__ _Float16 sAl[2][4096];
    __shared__ _Float16 sWh[2][12288];   // [buf][g(3)*n(64)][k(64)]
    __shared__ _Float16 sWl[2][12288];

    const int tid = threadIdx.x;
    const int wv = tid >> 6, lane = tid & 63;
    const int wm = wv >> 1, wn = wv & 1;
    const int ln = lane & 15, qd = lane >> 4;
    const int bid = blockIdx.x;
    const int n0 = (bid & 7) * 64;     // XCD-aligned n-tile
    const int m0 = (bid >> 3) * 64;
    const int total = itersI + itersH;

    float4v accH[4][2][2], accL[4][2][2];
    #pragma unroll
    for (int s = 0; s < 4; ++s)
        #pragma unroll
        for (int a = 0; a < 2; ++a)
            #pragma unroll
            for (int b = 0; b < 2; ++b) {
                accH[s][a][b] = (float4v)(0.f);
                accL[s][a][b] = (float4v)(0.f);
            }

    auto stage_tile = [&](int gt, int buf) {
        const bool ph = (gt >= itersI);
        const int it = ph ? gt - itersI : gt;
        const int k0 = it * 64;
        const _Float16* Ah_ = ph ? Ahh_ : Aih;
        const _Float16* Al_ = ph ? Ahl_ : Ail;
        const _Float16* Wh_ = ph ? Whh_ : Wih_;
        const _Float16* Wl_ = ph ? Whl_ : Wil_;
        const int ldA = ph ? H : ldAi;
        const int ldW = ph ? H : ldWi;
        #pragma unroll
        for (int j = 0; j < 2; ++j) {
            const int cid = wv * 128 + j * 64 + lane;
            const int m = cid >> 3, kc = cid & 7;
            const size_t off = (size_t)(m0 + m) * ldA + k0 + kc * 8;
            stage16(Ah_ + off, &sAh[buf][(wv * 128 + j * 64) * 8]);
            stage16(Al_ + off, &sAl[buf][(wv * 128 + j * 64) * 8]);
        }
        #pragma unroll
        for (int j = 0; j < 6; ++j) {
            const int cid = wv * 384 + j * 64 + lane;
            const int gg = cid >> 9, rem = cid & 511;
            const int nr = rem >> 3, kc = rem & 7;
            const size_t off = (size_t)(gg * H + n0 + nr) * ldW + k0 + kc * 8;
            stage16(Wh_ + off, &sWh[buf][(wv * 384 + j * 64) * 8]);
            stage16(Wl_ + off, &sWl[buf][(wv * 384 + j * 64) * 8]);
        }
    };

    // compute one K=64 tile; sN = acc set for the n-gate (2=i_n, 3=h_n)
    auto compute_tile = [&](int buf, const int sN) {
        #pragma unroll
        for (int ks = 0; ks < 2; ++ks) {
            half8 afh[2], afl[2];
            #pragma unroll
            for (int mt = 0; mt < 2; ++mt) {
                const int ai = (wm * 32 + mt * 16 + ln) * 64 + ks * 32 + qd * 8;
                afh[mt] = *(const half8*)&sAh[buf][ai];
                afl[mt] = *(const half8*)&sAl[buf][ai];
            }
            #pragma unroll
            for (int g = 0; g < 3; ++g) {
                const int s = (g < 2) ? g : sN;
                #pragma unroll
                for (int nt = 0; nt < 2; ++nt) {
                    const int wi = (g * 64 + wn * 32 + nt * 16 + ln) * 64 + ks * 32 + qd * 8;
                    half8 bh = *(const half8*)&sWh[buf][wi];
                    half8 bl = *(const half8*)&sWl[buf][wi];
                    #pragma unroll
                    for (int mt = 0; mt < 2; ++mt) {
                        accH[s][mt][nt] = __builtin_amdgcn_mfma_f32_16x16x32_f16(afh[mt], bh, accH[s][mt][nt], 0, 0, 0);
                        accL[s][mt][nt] = __builtin_amdgcn_mfma_f32_16x16x32_f16(afh[mt], bl, accL[s][mt][nt], 0, 0, 0);
                        accL[s][mt][nt] = __builtin_amdgcn_mfma_f32_16x16x32_f16(afl[mt], bh, accL[s][mt][nt], 0, 0, 0);
                    }
                }
            }
        }
    };

    stage_tile(0, 0);
    for (int gt = 0; gt < total; ++gt) {
        const int buf = gt & 1;
        __syncthreads();                       // drains this buf's async loads
        if (gt + 1 < total) stage_tile(gt + 1, buf ^ 1);   // prefetch overlaps compute
        if (gt < itersI) compute_tile(buf, 2);
        else             compute_tile(buf, 3);
    }

    // epilogue: C/D layout col=lane&15, row=qd*4+reg (verified m89/m91)
    #pragma unroll
    for (int nt = 0; nt < 2; ++nt) {
        const int gn = n0 + wn * 32 + nt * 16 + ln;
        const float bir = b_i[gn],         bhr = b_h[gn];
        const float biz = b_i[H + gn],     bhz = b_h[H + gn];
        const float bin = b_i[2 * H + gn], bhn = b_h[2 * H + gn];
        #pragma unroll
        for (int mt = 0; mt < 2; ++mt) {
            #pragma unroll
            for (int r = 0; r < 4; ++r) {
                const int m = m0 + wm * 32 + mt * 16 + qd * 4 + r;
                const float gR  = accH[0][mt][nt][r] + accL[0][mt][nt][r] * INV_LO + bir + bhr;
                const float gZ  = accH[1][mt][nt][r] + accL[1][mt][nt][r] * INV_LO + biz + bhz;
                const float gNi = accH[2][mt][nt][r] + accL[2][mt][nt][r] * INV_LO + bin;
                const float gNh = accH[3][mt][nt][r] + accL[3][mt][nt][r] * INV_LO + bhn;
                const float R = sigmoidf_(gR);
                const float Z = sigmoidf_(gZ);
                const float N = tanhf(fmaf(R, gNh, gNi));
                const size_t idx = (size_t)m * H + gn;
                const float hp = (float)hph[idx] + (float)hpl[idx] * INV_LO;
                const float hv = (1.f - Z) * N + Z * hp;
                split_f16(hv, &hnh[idx], &hnl[idx]);
            }
        }
    }
}

// ---------------- output projection + next-step xpad ----------------
// one wave per batch row: lanes hold 8 h-elements each, 5 dots, shuffle-reduce.
__global__ __launch_bounds__(256) void yout_kernel(
    const _Float16* __restrict__ h2h, const _Float16* __restrict__ h2l,
    const float* __restrict__ Wout, const float* __restrict__ bout,
    float* __restrict__ out, int t,
    const float* __restrict__ cmd_next,
    _Float16* __restrict__ xph, _Float16* __restrict__ xpl)
{
    const int wv = threadIdx.x >> 6, lane = threadIdx.x & 63;
    const int b = blockIdx.x * 4 + wv;
    const size_t hb = (size_t)b * H + lane * 8;
    half8 hh = *(const half8*)(h2h + hb);
    half8 hl = *(const half8*)(h2l + hb);
    float hv[8];
    #pragma unroll
    for (int j = 0; j < 8; ++j) hv[j] = (float)hh[j] + (float)hl[j] * INV_LO;
    float acc[NO];
    #pragma unroll
    for (int o = 0; o < NO; ++o) {
        acc[o] = 0.f;
        const float* w = Wout + (size_t)o * H + lane * 8;
        #pragma unroll
        for (int j = 0; j < 8; ++j) acc[o] = fmaf(hv[j], w[j], acc[o]);
    }
    #pragma unroll
    for (int off = 32; off > 0; off >>= 1)
        #pragma unroll
        for (int o = 0; o < NO; ++o) acc[o] += __shfl_down(acc[o], off, 64);
    if (lane == 0) {
        #pragma unroll
        for (int o = 0; o < NO; ++o) {
            const float y = acc[o] + bout[o];
            out[(size_t)b * (T * NO) + (size_t)t * NO + o] = y;
            split_f16(y, &xph[b * 64 + o], &xpl[b * 64 + o]);
        }
    } else if (lane >= NO && lane < 8) {
        split_f16(cmd_next[(size_t)b * NC + (lane - NO)],
                  &xph[b * 64 + lane], &xpl[b * 64 + lane]);
    }
}

extern "C" void kernel_launch(void* const* d_in, const int* in_sizes, int n_in,
                              void* d_out, int out_size, void* d_ws, size_t ws_size,
                              hipStream_t stream) {
    (void)in_sizes; (void)n_in; (void)out_size; (void)ws_size;
    const float* cmds  = (const float*)d_in[1];
    const float* y0    = (const float*)d_in[2];
    const float* h01   = (const float*)d_in[3];
    const float* h02   = (const float*)d_in[4];
    const float* W_ih1 = (const float*)d_in[5];
    const float* W_hh1 = (const float*)d_in[6];
    const float* b_ih1 = (const float*)d_in[7];
    const float* b_hh1 = (const float*)d_in[8];
    const float* W_ih2 = (const float*)d_in[9];
    const float* W_hh2 = (const float*)d_in[10];
    const float* b_ih2 = (const float*)d_in[11];
    const float* b_hh2 = (const float*)d_in[12];
    const float* W_out = (const float*)d_in[13];
    const float* b_out = (const float*)d_in[14];
    float* out = (float*)d_out;

    // ---- workspace layout (~27.1 MB) ----
    char* ws = (char*)d_ws;
    size_t o = 0;
    const size_t WSZ = (size_t)G3H * H * sizeof(_Float16);   // 1.57 MB
    _Float16* wh1h = (_Float16*)(ws + o); o += WSZ;
    _Float16* wh1l = (_Float16*)(ws + o); o += WSZ;
    _Float16* wi2h = (_Float16*)(ws + o); o += WSZ;
    _Float16* wi2l = (_Float16*)(ws + o); o += WSZ;
    _Float16* wh2h = (_Float16*)(ws + o); o += WSZ;
    _Float16* wh2l = (_Float16*)(ws + o); o += WSZ;
    _Float16* wi1ph = (_Float16*)(ws + o); o += (size_t)G3H * 64 * 2;
    _Float16* wi1pl = (_Float16*)(ws + o); o += (size_t)G3H * 64 * 2;
    _Float16* xph   = (_Float16*)(ws + o); o += (size_t)B * 64 * 2;
    _Float16* xpl   = (_Float16*)(ws + o); o += (size_t)B * 64 * 2;
    _Float16 *h1h[2], *h1l[2], *h2h[2], *h2l[2];
    for (int i = 0; i < 2; ++i) { h1h[i] = (_Float16*)(ws + o); o += (size_t)B * H * 2; }
    for (int i = 0; i < 2; ++i) { h1l[i] = (_Float16*)(ws + o); o += (size_t)B * H * 2; }
    for (int i = 0; i < 2; ++i) { h2h[i] = (_Float16*)(ws + o); o += (size_t)B * H * 2; }
    for (int i = 0; i < 2; ++i) { h2l[i] = (_Float16*)(ws + o); o += (size_t)B * H * 2; }

    // ---- prep (runs every launch; ws is re-poisoned before each timed call) ----
    conv3_kernel<<<(G3H * H + 255) / 256, 256, 0, stream>>>(
        W_hh1, W_ih2, W_hh2, wh1h, wh1l, wi2h, wi2l, wh2h, wh2l);
    prep_kernel<<<(B * H + 255) / 256, 256, 0, stream>>>(
        W_ih1, h01, h02, y0, cmds,
        wi1ph, wi1pl, h1h[0], h1l[0], h2h[0], h2l[0], xph, xpl);

    for (int t = 0; t < T; ++t) {
        const int si = t & 1;
        const int so = si ^ 1;

        // layer 1: gi = xpad @ wi1p^T (K=64), gh = h1_prev @ W_hh1^T (K=512)
        gru_cell_kernel<<<256, 256, 0, stream>>>(
            xph, xpl, 64, wi1ph, wi1pl, 64, 1,
            h1h[si], h1l[si], wh1h, wh1l, 8,
            b_ih1, b_hh1, h1h[si], h1l[si], h1h[so], h1l[so]);

        // layer 2: gi = h1_cur @ W_ih2^T (K=512), gh = h2_prev @ W_hh2^T (K=512)
        gru_cell_kernel<<<256, 256, 0, stream>>>(
            h1h[so], h1l[so], H, wi2h, wi2l, H, 8,
            h2h[si], h2l[si], wh2h, wh2l, 8,
            b_ih2, b_hh2, h2h[si], h2l[si], h2h[so], h2l[so]);

        const float* cmd_next = cmds + (size_t)((t + 1 < T) ? (t + 1) : t) * B * NC;
        yout_kernel<<<B / 4, 256, 0, stream>>>(
            h2h[so], h2l[so], W_out, b_out, out, t, cmd_next, xph, xpl);
    }
}